// Round 3
// baseline (733.961 us; speedup 1.0000x reference)
//
#include <hip/hip_runtime.h>
#include <math.h>

#define CH_IN   512
#define CH_OUT  256
#define HWD     4096
#define BATCH   32
#define MAXSLOT 32   // ptr can never exceed 32: at most one append per batch step

typedef __attribute__((ext_vector_type(8))) short short8;
typedef __attribute__((ext_vector_type(4))) float floatx4;

// fp32 -> bf16 RNE, packed pair into one uint (low = a, high = b)
__device__ __forceinline__ unsigned int pk_bf16(float a, float b) {
    unsigned int ua = __float_as_uint(a);
    ua += 0x7fffu + ((ua >> 16) & 1u);
    unsigned int ub = __float_as_uint(b);
    ub += 0x7fffu + ((ub >> 16) & 1u);
    return (ua >> 16) | (ub & 0xffff0000u);
}

// ---------------------------------------------------------------------------
// Kernel 1: proj = W @ feats + b  via bf16 MFMA 16x16x32, fp32 accumulate.
// Block: 256 thr = 4 waves (2x2), tile 128o x 128l, BK=32.
// Grid: 2048 linear, XCD-aware decode: the two ot-blocks of a (lt,b) tile
// occupy consecutive slots of the SAME XCD -> second feats read is an L2 hit.
// LDS: As[o][c] pitch 40 bf16, Bs[l][c] pitch 42 bf16.
// Fused: pooled[b][o] += sum_l proj*preds (mean applied in k2).
// ---------------------------------------------------------------------------
#define PA 40
#define PB 42
__global__ __launch_bounds__(256) void k1_proj_gemm(
    const float* __restrict__ feats, const float* __restrict__ preds,
    const float* __restrict__ W, const float* __restrict__ bias,
    float* __restrict__ out, float* __restrict__ pooled)
{
    __shared__ __align__(16) unsigned short As[128 * PA];
    __shared__ __align__(16) unsigned short Bs[128 * PB];

    const int t  = threadIdx.x;
    // XCD-aware decode: xcd = bid%8 (round-robin mapping), 256 slots per XCD.
    // tile = xcd*128 + slot/2, ot = slot%2  -> ot-pair adjacent on one XCD.
    const int bid  = blockIdx.x;
    const int xcd  = bid & 7;
    const int slot = bid >> 3;                 // 0..255
    const int tile = xcd * 128 + (slot >> 1);  // 0..1023
    const int ot   = slot & 1;
    const int lt   = tile & 31;
    const int b    = tile >> 5;

    const int l0 = lt * 128, o0 = ot * 128;
    const int lane = t & 63, wid = t >> 6;
    const int wm = wid & 1, wn = wid >> 1;       // wave 2x2 grid
    const int ln = lane & 15, quad = lane >> 4;

    floatx4 acc[4][4];
    #pragma unroll
    for (int i = 0; i < 4; i++)
        #pragma unroll
        for (int j = 0; j < 4; j++) acc[i][j] = (floatx4){0.f, 0.f, 0.f, 0.f};

    const float* Wb = W + (size_t)o0 * CH_IN;
    const float* Fb = feats + (size_t)b * CH_IN * HWD + l0;

    // B staging mapping: thread owns 4c x 4l micro-block
    const int l4 = t & 31;      // l = l4*4 + i
    const int cg = t >> 5;      // c = cg*4 + j

    for (int k0 = 0; k0 < CH_IN; k0 += 32) {
        // ---- stage A: W tile 128o x 32c ----
        #pragma unroll
        for (int q = 0; q < 4; q++) {
            int idx = t + 256 * q;
            int o = idx >> 3, c4 = idx & 7;
            float4 w = *(const float4*)(Wb + (size_t)o * CH_IN + k0 + c4 * 4);
            unsigned int u0 = pk_bf16(w.x, w.y);
            unsigned int u1 = pk_bf16(w.z, w.w);
            *(uint2*)(As + o * PA + c4 * 4) = make_uint2(u0, u1);
        }
        // ---- stage B: feats tile 32c x 128l, transposed to Bs[l][c] ----
        float4 f0 = *(const float4*)(Fb + (size_t)(k0 + cg * 4 + 0) * HWD + l4 * 4);
        float4 f1 = *(const float4*)(Fb + (size_t)(k0 + cg * 4 + 1) * HWD + l4 * 4);
        float4 f2 = *(const float4*)(Fb + (size_t)(k0 + cg * 4 + 2) * HWD + l4 * 4);
        float4 f3 = *(const float4*)(Fb + (size_t)(k0 + cg * 4 + 3) * HWD + l4 * 4);
        {
            const float v0[4] = {f0.x, f0.y, f0.z, f0.w};
            const float v1[4] = {f1.x, f1.y, f1.z, f1.w};
            const float v2[4] = {f2.x, f2.y, f2.z, f2.w};
            const float v3[4] = {f3.x, f3.y, f3.z, f3.w};
            #pragma unroll
            for (int i = 0; i < 4; i++) {
                unsigned short* row = Bs + (l4 * 4 + i) * PB + cg * 4;
                *(unsigned int*)(row)     = pk_bf16(v0[i], v1[i]);
                *(unsigned int*)(row + 2) = pk_bf16(v2[i], v3[i]);
            }
        }
        __syncthreads();

        // ---- fragments + MFMA ----
        short8 af[4], bf[4];
        #pragma unroll
        for (int mt = 0; mt < 4; mt++) {
            int row = wm * 64 + mt * 16 + ln;
            af[mt] = *(const short8*)(As + row * PA + quad * 8);
        }
        #pragma unroll
        for (int nt = 0; nt < 4; nt++) {
            int row = wn * 64 + nt * 16 + ln;
            const unsigned short* p = Bs + row * PB + quad * 8;
            union { short8 v; unsigned int u[4]; } r;
            r.u[0] = *(const unsigned int*)(p);
            r.u[1] = *(const unsigned int*)(p + 2);
            r.u[2] = *(const unsigned int*)(p + 4);
            r.u[3] = *(const unsigned int*)(p + 6);
            bf[nt] = r.v;
        }
        #pragma unroll
        for (int mt = 0; mt < 4; mt++)
            #pragma unroll
            for (int nt = 0; nt < 4; nt++)
                acc[mt][nt] = __builtin_amdgcn_mfma_f32_16x16x32_bf16(
                    af[mt], bf[nt], acc[mt][nt], 0, 0, 0);
        __syncthreads();
    }

    // ---- epilogue: bias add, store proj, fused pooled partials ----
    float pv[4];
    #pragma unroll
    for (int nt = 0; nt < 4; nt++)
        pv[nt] = preds[(size_t)b * HWD + l0 + wn * 64 + nt * 16 + ln];

    #pragma unroll
    for (int mt = 0; mt < 4; mt++) {
        #pragma unroll
        for (int r = 0; r < 4; r++) {
            int o = o0 + wm * 64 + mt * 16 + quad * 4 + r;
            float bv = bias[o];
            float* op = out + ((size_t)b * 512 + o) * HWD + l0 + wn * 64;
            float psum = 0.f;
            #pragma unroll
            for (int nt = 0; nt < 4; nt++) {
                float val = acc[mt][nt][r] + bv;
                op[nt * 16 + ln] = val;
                psum += val * pv[nt];
            }
            #pragma unroll
            for (int off = 1; off < 16; off <<= 1)
                psum += __shfl_xor(psum, off, 64);
            if (ln == 0)
                atomicAdd(&pooled[(size_t)b * CH_OUT + o], psum);
        }
    }
}

// ---------------------------------------------------------------------------
// Kernel 2: sequential codebook update (one block; memory fits in LDS).
// 1024 threads = 16 waves: sims phase strides p += 16 (<=2 rounds vs <=8),
// per-slot dot expression + shfl tree UNCHANGED -> bitwise-identical sims.
// Channel-parallel phases (load/update/norm) guarded to t < 256.
// ---------------------------------------------------------------------------
__global__ __launch_bounds__(1024) void k2_mem_update(
    const float* __restrict__ pooled, const int* __restrict__ epoch_p,
    float* __restrict__ mem_out, int* __restrict__ ptr_out)
{
    __shared__ float mem[MAXSLOT][256];
    __shared__ float xs[256];
    __shared__ float norms2[MAXSLOT];
    __shared__ float sims[MAXSLOT];
    __shared__ float red[4];
    __shared__ float xnorm2_s;
    __shared__ int ptr_s, row_s, ema_s;

    const int t = threadIdx.x;
    const int lane = t & 63, wid = t >> 6;   // wid 0..15

    if (t < 256)
        for (int r = 0; r < MAXSLOT; r++) mem[r][t] = 0.f;
    if (t < MAXSLOT) norms2[t] = 0.f;
    if (t == 0) ptr_s = 0;

    double thr_d = ((double)(*epoch_p)) / 10.0 - 2.0;
    thr_d = thr_d * 0.4 / 13.0 + 0.3;
    const float thr = (float)thr_d;
    __syncthreads();

    for (int bi = 0; bi < BATCH; bi++) {
        if (t < 256) {
            float x = pooled[(size_t)bi * 256 + t] * (1.0f / 4096.0f);
            xs[t] = x;
            float s = x * x;
            #pragma unroll
            for (int off = 32; off >= 1; off >>= 1) s += __shfl_xor(s, off, 64);
            if (lane == 0) red[wid] = s;
        }
        __syncthreads();
        if (t == 0) xnorm2_s = red[0] + red[1] + red[2] + red[3];
        __syncthreads();

        const int P = ptr_s;
        const float xn = sqrtf(xnorm2_s);
        for (int p = wid; p < P; p += 16) {
            float d = mem[p][lane]       * xs[lane]
                    + mem[p][lane + 64]  * xs[lane + 64]
                    + mem[p][lane + 128] * xs[lane + 128]
                    + mem[p][lane + 192] * xs[lane + 192];
            #pragma unroll
            for (int off = 32; off >= 1; off >>= 1) d += __shfl_xor(d, off, 64);
            if (lane == 0) {
                float nrm = sqrtf(norms2[p]);
                if (nrm == 0.f) nrm = 1.f;
                sims[p] = d / (nrm * xn);
            }
        }
        __syncthreads();

        if (wid == 0) {
            float v = (lane < P) ? sims[lane] : -INFINITY;
            int idx = lane;
            #pragma unroll
            for (int off = 32; off >= 1; off >>= 1) {
                float ov = __shfl_down(v, off, 64);
                int   oi = __shfl_down(idx, off, 64);
                if (ov > v || (ov == v && oi < idx)) { v = ov; idx = oi; }
            }
            if (lane == 0) {
                int ema = (P > 0 && v >= thr) ? 1 : 0;
                ema_s = ema;
                row_s = ema ? idx : P;
                if (!ema) ptr_s = P + 1;
            }
        }
        __syncthreads();

        const int r = row_s;
        if (t < 256) {
            float nv = ema_s ? (mem[r][t] * 0.9f + 0.1f * xs[t]) : xs[t];
            mem[r][t] = nv;
            float s2 = nv * nv;
            #pragma unroll
            for (int off = 32; off >= 1; off >>= 1) s2 += __shfl_xor(s2, off, 64);
            if (lane == 0) red[wid] = s2;
        }
        __syncthreads();
        if (t == 0) norms2[r] = red[0] + red[1] + red[2] + red[3];
        __syncthreads();
    }

    if (t < 256)
        for (int r = 0; r < MAXSLOT; r++) mem_out[(size_t)r * 256 + t] = mem[r][t];
    if (t == 0) ptr_out[0] = ptr_s;
}

// ---------------------------------------------------------------------------
// Kernel 3: memory cross-attention. Block = (b, 128 l-columns).
// LDS = 16.9 KB (attnL only) -> 8 blocks/CU allowed; all 4 blocks/CU of work
// co-resident -> latency hidden by TLP. mem is read via L1/L2-cached global
// float4 broadcasts (all-lane-uniform addresses), no memL staging.
// Phase A: thread tile 4 slots x 4 l (tx=t&31 -> conflict-free ds_read_b128);
//          proj chunks (32c x 128l) LDS-staged once, reg double-buffered.
//          Per-logit c-accumulation order 0..255 unchanged -> bitwise-identical.
// Phase B: softmax over slots per column (threads 0..127).
// Phase C: aug[c][l]; mem from global broadcasts, attn re-read from LDS.
// ---------------------------------------------------------------------------
#define PT 132   // attnL pitch (staging rows 32c x 128l, then logits 32p x 128l)

#define K3_FMA4(MI, PV, AI) \
    AI[0] = fmaf(MI, PV.x, AI[0]); \
    AI[1] = fmaf(MI, PV.y, AI[1]); \
    AI[2] = fmaf(MI, PV.z, AI[2]); \
    AI[3] = fmaf(MI, PV.w, AI[3]);

__global__ __launch_bounds__(256) void k3_attention(
    const float* __restrict__ mem_g, const int* __restrict__ ptr_g,
    float* __restrict__ out)
{
    __shared__ __align__(16) float attnL[MAXSLOT * PT];

    const int t = threadIdx.x;
    const int lt = blockIdx.x, b = blockIdx.y;
    const int l0 = lt * 128;
    const int P = ptr_g[0];

    // ---- phase A: logits, thread tile 4 slots x 4 l, LDS-staged proj ----
    {
        const int tx = t & 31;        // compute role: l = tx*4 .. +3
        const int py = t >> 5;        // compute role: p0 = py*4
        const int p0 = py * 4;
        const int sl4 = t & 31;       // staging role: l = sl4*4
        const int scw = t >> 5;       // staging role: c = scw + q*8

        const float* projB = out + (size_t)b * 512 * HWD + l0;
        float a0[4], a1[4], a2[4], a3[4];
        #pragma unroll
        for (int j = 0; j < 4; j++) { a0[j] = 0.f; a1[j] = 0.f; a2[j] = 0.f; a3[j] = 0.f; }

        const float* m0p = mem_g + (size_t)(p0 + 0) * 256;
        const float* m1p = mem_g + (size_t)(p0 + 1) * 256;
        const float* m2p = mem_g + (size_t)(p0 + 2) * 256;
        const float* m3p = mem_g + (size_t)(p0 + 3) * 256;

        // reg double-buffer for staging (T14: issue early, write late)
        float4 st[4];
        #pragma unroll
        for (int q = 0; q < 4; q++)
            st[q] = *(const float4*)(projB + (size_t)(scw + q * 8) * HWD + sl4 * 4);

        for (int c0 = 0; c0 < 256; c0 += 32) {
            __syncthreads();   // previous chunk fully consumed
            #pragma unroll
            for (int q = 0; q < 4; q++)
                *(float4*)(attnL + (scw + q * 8) * PT + sl4 * 4) = st[q];
            __syncthreads();   // chunk visible to all
            if (c0 + 32 < 256) {
                #pragma unroll
                for (int q = 0; q < 4; q++)
                    st[q] = *(const float4*)(projB +
                        (size_t)(c0 + 32 + scw + q * 8) * HWD + sl4 * 4);
            }
            #pragma unroll 2
            for (int cc = 0; cc < 32; cc += 4) {
                const int c = c0 + cc;
                float4 m0 = *(const float4*)(m0p + c);
                float4 m1 = *(const float4*)(m1p + c);
                float4 m2 = *(const float4*)(m2p + c);
                float4 m3 = *(const float4*)(m3p + c);
                {
                    float4 pv = *(const float4*)(attnL + (cc + 0) * PT + tx * 4);
                    K3_FMA4(m0.x, pv, a0) K3_FMA4(m1.x, pv, a1)
                    K3_FMA4(m2.x, pv, a2) K3_FMA4(m3.x, pv, a3)
                }
                {
                    float4 pv = *(const float4*)(attnL + (cc + 1) * PT + tx * 4);
                    K3_FMA4(m0.y, pv, a0) K3_FMA4(m1.y, pv, a1)
                    K3_FMA4(m2.y, pv, a2) K3_FMA4(m3.y, pv, a3)
                }
                {
                    float4 pv = *(const float4*)(attnL + (cc + 2) * PT + tx * 4);
                    K3_FMA4(m0.z, pv, a0) K3_FMA4(m1.z, pv, a1)
                    K3_FMA4(m2.z, pv, a2) K3_FMA4(m3.z, pv, a3)
                }
                {
                    float4 pv = *(const float4*)(attnL + (cc + 3) * PT + tx * 4);
                    K3_FMA4(m0.w, pv, a0) K3_FMA4(m1.w, pv, a1)
                    K3_FMA4(m2.w, pv, a2) K3_FMA4(m3.w, pv, a3)
                }
            }
        }
        __syncthreads();       // last chunk consumed everywhere before overwrite
        #pragma unroll
        for (int j = 0; j < 4; j++) {
            attnL[(p0 + 0) * PT + tx * 4 + j] = a0[j];
            attnL[(p0 + 1) * PT + tx * 4 + j] = a1[j];
            attnL[(p0 + 2) * PT + tx * 4 + j] = a2[j];
            attnL[(p0 + 3) * PT + tx * 4 + j] = a3[j];
        }
    }
    __syncthreads();

    // ---- phase B: softmax over valid slots, per column ----
    if (t < 128) {
        float m = -INFINITY;
        for (int p = 0; p < P; p++) m = fmaxf(m, attnL[p * PT + t]);
        float d = 0.f;
        for (int p = 0; p < P; p++) {
            float e = __expf(attnL[p * PT + t] - m);
            attnL[p * PT + t] = e;
            d += e;
        }
        float inv = 1.f / d;
        for (int p = 0; p < P; p++) attnL[p * PT + t] *= inv;
    }
    __syncthreads();

    // ---- phase C: aug[c][l] = sum_p attn[p][l]*mem[p][c] ----
    {
        const int lC = t & 127;
        const int h = t >> 7;         // c half
        const int c0 = h * 128;
        const float* attC = attnL + lC;
        const float* memB = mem_g + c0;

        float* augB = out + ((size_t)b * 512 + 256 + c0) * HWD + l0 + lC;
        for (int cc = 0; cc < 128; cc += 8) {
            float acc[8];
            #pragma unroll
            for (int j = 0; j < 8; j++) acc[j] = 0.f;
            for (int p = 0; p < P; p++) {
                float4 mA = *(const float4*)(memB + (size_t)p * 256 + cc);
                float4 mB = *(const float4*)(memB + (size_t)p * 256 + cc + 4);
                float a = attC[p * PT];
                acc[0] = fmaf(a, mA.x, acc[0]);
                acc[1] = fmaf(a, mA.y, acc[1]);
                acc[2] = fmaf(a, mA.z, acc[2]);
                acc[3] = fmaf(a, mA.w, acc[3]);
                acc[4] = fmaf(a, mB.x, acc[4]);
                acc[5] = fmaf(a, mB.y, acc[5]);
                acc[6] = fmaf(a, mB.z, acc[6]);
                acc[7] = fmaf(a, mB.w, acc[7]);
            }
            #pragma unroll
            for (int j = 0; j < 8; j++)
                augB[(size_t)(cc + j) * HWD] = acc[j];
        }
    }
}

// ---------------------------------------------------------------------------
extern "C" void kernel_launch(void* const* d_in, const int* in_sizes, int n_in,
                              void* d_out, int out_size, void* d_ws, size_t ws_size,
                              hipStream_t stream) {
    const float* feats = (const float*)d_in[0];
    const float* preds = (const float*)d_in[1];
    const float* W     = (const float*)d_in[2];
    const float* bias  = (const float*)d_in[3];
    const int*   epoch = (const int*)d_in[4];
    float* out = (float*)d_out;

    float* ws     = (float*)d_ws;
    float* pooled = ws;              // 32*256 floats (accumulated via atomics)
    float* mem_g  = ws + 8192;       // 32*256 floats
    int*   ptr_g  = (int*)(ws + 16384);

    hipMemsetAsync(pooled, 0, 8192 * sizeof(float), stream);

    k1_proj_gemm<<<dim3(2048), 256, 0, stream>>>(feats, preds, W, bias, out, pooled);
    k2_mem_update<<<1, 1024, 0, stream>>>(pooled, epoch, mem_g, ptr_g);
    k3_attention<<<dim3(32, 32), 256, 0, stream>>>(mem_g, ptr_g, out);
}

// Round 7
// 592.849 us; speedup vs baseline: 1.2380x; 1.2380x over previous
//
#include <hip/hip_runtime.h>
#include <math.h>

#define CH_IN   512
#define CH_OUT  256
#define HWD     4096
#define BATCH   32
#define MAXSLOT 32   // ptr can never exceed 32: at most one append per batch step

typedef __attribute__((ext_vector_type(8))) short short8;
typedef __attribute__((ext_vector_type(4))) float floatx4;

// fp32 -> bf16 RNE, packed pair into one uint (low = a, high = b)
__device__ __forceinline__ unsigned int pk_bf16(float a, float b) {
    unsigned int ua = __float_as_uint(a);
    ua += 0x7fffu + ((ua >> 16) & 1u);
    unsigned int ub = __float_as_uint(b);
    ub += 0x7fffu + ((ub >> 16) & 1u);
    return (ua >> 16) | (ub & 0xffff0000u);
}

// ---------------------------------------------------------------------------
// Kernel 1: proj = W @ feats + b  via bf16 MFMA 16x16x32, fp32 accumulate.
// Block: 256 thr = 4 waves (2x2), tile 128o x 128l, BK=32.
// Grid: 2048 linear, XCD-aware decode: the two ot-blocks of a (lt,b) tile
// occupy consecutive slots of the SAME XCD -> second feats read is an L2 hit.
// LDS: As[o][c] pitch 40 bf16, Bs[l][c] pitch 42 bf16.
// Fused: pooled[b][o] += sum_l proj*preds (mean applied in k2).
// ---------------------------------------------------------------------------
#define PA 40
#define PB 42
__global__ __launch_bounds__(256) void k1_proj_gemm(
    const float* __restrict__ feats, const float* __restrict__ preds,
    const float* __restrict__ W, const float* __restrict__ bias,
    float* __restrict__ out, float* __restrict__ pooled)
{
    __shared__ __align__(16) unsigned short As[128 * PA];
    __shared__ __align__(16) unsigned short Bs[128 * PB];

    const int t  = threadIdx.x;
    // XCD-aware decode: xcd = bid%8 (round-robin mapping), 256 slots per XCD.
    // tile = xcd*128 + slot/2, ot = slot%2  -> ot-pair adjacent on one XCD.
    const int bid  = blockIdx.x;
    const int xcd  = bid & 7;
    const int slot = bid >> 3;                 // 0..255
    const int tile = xcd * 128 + (slot >> 1);  // 0..1023
    const int ot   = slot & 1;
    const int lt   = tile & 31;
    const int b    = tile >> 5;

    const int l0 = lt * 128, o0 = ot * 128;
    const int lane = t & 63, wid = t >> 6;
    const int wm = wid & 1, wn = wid >> 1;       // wave 2x2 grid
    const int ln = lane & 15, quad = lane >> 4;

    floatx4 acc[4][4];
    #pragma unroll
    for (int i = 0; i < 4; i++)
        #pragma unroll
        for (int j = 0; j < 4; j++) acc[i][j] = (floatx4){0.f, 0.f, 0.f, 0.f};

    const float* Wb = W + (size_t)o0 * CH_IN;
    const float* Fb = feats + (size_t)b * CH_IN * HWD + l0;

    // B staging mapping: thread owns 4c x 4l micro-block
    const int l4 = t & 31;      // l = l4*4 + i
    const int cg = t >> 5;      // c = cg*4 + j

    for (int k0 = 0; k0 < CH_IN; k0 += 32) {
        // ---- stage A: W tile 128o x 32c ----
        #pragma unroll
        for (int q = 0; q < 4; q++) {
            int idx = t + 256 * q;
            int o = idx >> 3, c4 = idx & 7;
            float4 w = *(const float4*)(Wb + (size_t)o * CH_IN + k0 + c4 * 4);
            unsigned int u0 = pk_bf16(w.x, w.y);
            unsigned int u1 = pk_bf16(w.z, w.w);
            *(uint2*)(As + o * PA + c4 * 4) = make_uint2(u0, u1);
        }
        // ---- stage B: feats tile 32c x 128l, transposed to Bs[l][c] ----
        float4 f0 = *(const float4*)(Fb + (size_t)(k0 + cg * 4 + 0) * HWD + l4 * 4);
        float4 f1 = *(const float4*)(Fb + (size_t)(k0 + cg * 4 + 1) * HWD + l4 * 4);
        float4 f2 = *(const float4*)(Fb + (size_t)(k0 + cg * 4 + 2) * HWD + l4 * 4);
        float4 f3 = *(const float4*)(Fb + (size_t)(k0 + cg * 4 + 3) * HWD + l4 * 4);
        {
            const float v0[4] = {f0.x, f0.y, f0.z, f0.w};
            const float v1[4] = {f1.x, f1.y, f1.z, f1.w};
            const float v2[4] = {f2.x, f2.y, f2.z, f2.w};
            const float v3[4] = {f3.x, f3.y, f3.z, f3.w};
            #pragma unroll
            for (int i = 0; i < 4; i++) {
                unsigned short* row = Bs + (l4 * 4 + i) * PB + cg * 4;
                *(unsigned int*)(row)     = pk_bf16(v0[i], v1[i]);
                *(unsigned int*)(row + 2) = pk_bf16(v2[i], v3[i]);
            }
        }
        __syncthreads();

        // ---- fragments + MFMA ----
        short8 af[4], bf[4];
        #pragma unroll
        for (int mt = 0; mt < 4; mt++) {
            int row = wm * 64 + mt * 16 + ln;
            af[mt] = *(const short8*)(As + row * PA + quad * 8);
        }
        #pragma unroll
        for (int nt = 0; nt < 4; nt++) {
            int row = wn * 64 + nt * 16 + ln;
            const unsigned short* p = Bs + row * PB + quad * 8;
            union { short8 v; unsigned int u[4]; } r;
            r.u[0] = *(const unsigned int*)(p);
            r.u[1] = *(const unsigned int*)(p + 2);
            r.u[2] = *(const unsigned int*)(p + 4);
            r.u[3] = *(const unsigned int*)(p + 6);
            bf[nt] = r.v;
        }
        #pragma unroll
        for (int mt = 0; mt < 4; mt++)
            #pragma unroll
            for (int nt = 0; nt < 4; nt++)
                acc[mt][nt] = __builtin_amdgcn_mfma_f32_16x16x32_bf16(
                    af[mt], bf[nt], acc[mt][nt], 0, 0, 0);
        __syncthreads();
    }

    // ---- epilogue: bias add, store proj, fused pooled partials ----
    float pv[4];
    #pragma unroll
    for (int nt = 0; nt < 4; nt++)
        pv[nt] = preds[(size_t)b * HWD + l0 + wn * 64 + nt * 16 + ln];

    #pragma unroll
    for (int mt = 0; mt < 4; mt++) {
        #pragma unroll
        for (int r = 0; r < 4; r++) {
            int o = o0 + wm * 64 + mt * 16 + quad * 4 + r;
            float bv = bias[o];
            float* op = out + ((size_t)b * 512 + o) * HWD + l0 + wn * 64;
            float psum = 0.f;
            #pragma unroll
            for (int nt = 0; nt < 4; nt++) {
                float val = acc[mt][nt][r] + bv;
                op[nt * 16 + ln] = val;
                psum += val * pv[nt];
            }
            #pragma unroll
            for (int off = 1; off < 16; off <<= 1)
                psum += __shfl_xor(psum, off, 64);
            if (ln == 0)
                atomicAdd(&pooled[(size_t)b * CH_OUT + o], psum);
        }
    }
}

// ---------------------------------------------------------------------------
// Kernel 2: sequential codebook update (one block; memory fits in LDS).
// 1024 threads = 16 waves: sims phase strides p += 16 (<=2 rounds vs <=8),
// per-slot dot expression + shfl tree UNCHANGED -> bitwise-identical sims.
// Channel-parallel phases (load/update/norm) guarded to t < 256.
// ---------------------------------------------------------------------------
__global__ __launch_bounds__(1024) void k2_mem_update(
    const float* __restrict__ pooled, const int* __restrict__ epoch_p,
    float* __restrict__ mem_out, int* __restrict__ ptr_out)
{
    __shared__ float mem[MAXSLOT][256];
    __shared__ float xs[256];
    __shared__ float norms2[MAXSLOT];
    __shared__ float sims[MAXSLOT];
    __shared__ float red[4];
    __shared__ float xnorm2_s;
    __shared__ int ptr_s, row_s, ema_s;

    const int t = threadIdx.x;
    const int lane = t & 63, wid = t >> 6;   // wid 0..15

    if (t < 256)
        for (int r = 0; r < MAXSLOT; r++) mem[r][t] = 0.f;
    if (t < MAXSLOT) norms2[t] = 0.f;
    if (t == 0) ptr_s = 0;

    double thr_d = ((double)(*epoch_p)) / 10.0 - 2.0;
    thr_d = thr_d * 0.4 / 13.0 + 0.3;
    const float thr = (float)thr_d;
    __syncthreads();

    for (int bi = 0; bi < BATCH; bi++) {
        if (t < 256) {
            float x = pooled[(size_t)bi * 256 + t] * (1.0f / 4096.0f);
            xs[t] = x;
            float s = x * x;
            #pragma unroll
            for (int off = 32; off >= 1; off >>= 1) s += __shfl_xor(s, off, 64);
            if (lane == 0) red[wid] = s;
        }
        __syncthreads();
        if (t == 0) xnorm2_s = red[0] + red[1] + red[2] + red[3];
        __syncthreads();

        const int P = ptr_s;
        const float xn = sqrtf(xnorm2_s);
        for (int p = wid; p < P; p += 16) {
            float d = mem[p][lane]       * xs[lane]
                    + mem[p][lane + 64]  * xs[lane + 64]
                    + mem[p][lane + 128] * xs[lane + 128]
                    + mem[p][lane + 192] * xs[lane + 192];
            #pragma unroll
            for (int off = 32; off >= 1; off >>= 1) d += __shfl_xor(d, off, 64);
            if (lane == 0) {
                float nrm = sqrtf(norms2[p]);
                if (nrm == 0.f) nrm = 1.f;
                sims[p] = d / (nrm * xn);
            }
        }
        __syncthreads();

        if (wid == 0) {
            float v = (lane < P) ? sims[lane] : -INFINITY;
            int idx = lane;
            #pragma unroll
            for (int off = 32; off >= 1; off >>= 1) {
                float ov = __shfl_down(v, off, 64);
                int   oi = __shfl_down(idx, off, 64);
                if (ov > v || (ov == v && oi < idx)) { v = ov; idx = oi; }
            }
            if (lane == 0) {
                int ema = (P > 0 && v >= thr) ? 1 : 0;
                ema_s = ema;
                row_s = ema ? idx : P;
                if (!ema) ptr_s = P + 1;
            }
        }
        __syncthreads();

        const int r = row_s;
        if (t < 256) {
            float nv = ema_s ? (mem[r][t] * 0.9f + 0.1f * xs[t]) : xs[t];
            mem[r][t] = nv;
            float s2 = nv * nv;
            #pragma unroll
            for (int off = 32; off >= 1; off >>= 1) s2 += __shfl_xor(s2, off, 64);
            if (lane == 0) red[wid] = s2;
        }
        __syncthreads();
        if (t == 0) norms2[r] = red[0] + red[1] + red[2] + red[3];
        __syncthreads();
    }

    if (t < 256)
        for (int r = 0; r < MAXSLOT; r++) mem_out[(size_t)r * 256 + t] = mem[r][t];
    if (t == 0) ptr_out[0] = ptr_s;
}

// ---------------------------------------------------------------------------
// Kernel 3: memory cross-attention, MFMA for both GEMM phases.
//   phase A: logits[32p,128l] = mem[32,256] @ proj[256,128]  (bf16 MFMA, 8 K-steps)
//   phase B: softmax over slots per column (threads 0..127), fp32, unchanged
//   phase C: aug[256c,128l] = memT[256,32] @ attn[32,128]    (bf16 MFMA, 1 K-step)
// Fragment geometry (A pitch-40 reads, B pitch-42 union reads, C-layout) is
// copied verbatim from harness-proven k1. memS buffer (20.5KB) holds memA
// (K-chunked [8][32][40]) for phase A, then is overwritten with memT
// ([256][40]) for phase C. attn rows p>=P are zeroed at bf16 conversion
// (== reference -inf masking). LDS 48.1KB -> 3 blocks/CU.
// ---------------------------------------------------------------------------
#define PT  132  // attnL pitch (fp32 logits 32p x 128l)
#define PMS 40   // memS row pitch (shorts)
#define PBS 42   // Bs row pitch (shorts)
__global__ __launch_bounds__(256) void k3_attention(
    const float* __restrict__ mem_g, const int* __restrict__ ptr_g,
    float* __restrict__ out)
{
    __shared__ __align__(16) unsigned short memS[10240];     // 20480 B
    __shared__ __align__(16) unsigned short Bs[128 * PBS];   // 10752 B
    __shared__ __align__(16) float attnL[MAXSLOT * PT];      // 16896 B

    const int t = threadIdx.x;
    const int lt = blockIdx.x, b = blockIdx.y;
    const int l0 = lt * 128;
    const int P = ptr_g[0];

    const int lane = t & 63, wid = t >> 6;
    const int wm = wid & 1, wn = wid >> 1;       // wave 2x2 grid
    const int ln = lane & 15, quad = lane >> 4;

    // ---- stage memA: mem_g[32p][256c] fp32 -> memS[k][32p][40] bf16 ----
    #pragma unroll
    for (int q = 0; q < 16; q++) {
        int idx = t + 256 * q;                 // 0..4095
        int p = idx >> 7, cp = idx & 127;      // c = 2*cp
        float2 v = *(const float2*)(mem_g + (size_t)p * 256 + cp * 2);
        *(unsigned int*)(memS + (cp >> 4) * (32 * PMS) + p * PMS + (cp & 15) * 2)
            = pk_bf16(v.x, v.y);
    }

    const float* Pb = out + (size_t)b * 512 * HWD + l0;
    const int l4 = t & 31;      // staging: l = l4*4 + i
    const int cg = t >> 5;      // staging: c = cg*4 + j

    floatx4 accA[4];
    #pragma unroll
    for (int nt = 0; nt < 4; nt++) accA[nt] = (floatx4){0.f, 0.f, 0.f, 0.f};

    // ---- phase A K-loop: 8 chunks of 32 c ----
    for (int k0 = 0; k0 < 8; k0++) {
        // stage proj chunk [32c][128l] -> Bs[l][c] bf16 (k1's proven stage-B)
        float4 f0 = *(const float4*)(Pb + (size_t)(k0 * 32 + cg * 4 + 0) * HWD + l4 * 4);
        float4 f1 = *(const float4*)(Pb + (size_t)(k0 * 32 + cg * 4 + 1) * HWD + l4 * 4);
        float4 f2 = *(const float4*)(Pb + (size_t)(k0 * 32 + cg * 4 + 2) * HWD + l4 * 4);
        float4 f3 = *(const float4*)(Pb + (size_t)(k0 * 32 + cg * 4 + 3) * HWD + l4 * 4);
        {
            const float v0[4] = {f0.x, f0.y, f0.z, f0.w};
            const float v1[4] = {f1.x, f1.y, f1.z, f1.w};
            const float v2[4] = {f2.x, f2.y, f2.z, f2.w};
            const float v3[4] = {f3.x, f3.y, f3.z, f3.w};
            #pragma unroll
            for (int i = 0; i < 4; i++) {
                unsigned short* row = Bs + (l4 * 4 + i) * PBS + cg * 4;
                *(unsigned int*)(row)     = pk_bf16(v0[i], v1[i]);
                *(unsigned int*)(row + 2) = pk_bf16(v2[i], v3[i]);
            }
        }
        __syncthreads();

        // A-frag: mem row (wm*16+ln), k-chunk k0, shorts quad*8..+7
        short8 af = *(const short8*)(memS + k0 * (32 * PMS) + (wm * 16 + ln) * PMS + quad * 8);
        short8 bf[4];
        #pragma unroll
        for (int nt = 0; nt < 4; nt++) {
            const unsigned short* p = Bs + (wn * 64 + nt * 16 + ln) * PBS + quad * 8;
            union { short8 v; unsigned int u[4]; } r;
            r.u[0] = *(const unsigned int*)(p);
            r.u[1] = *(const unsigned int*)(p + 2);
            r.u[2] = *(const unsigned int*)(p + 4);
            r.u[3] = *(const unsigned int*)(p + 6);
            bf[nt] = r.v;
        }
        #pragma unroll
        for (int nt = 0; nt < 4; nt++)
            accA[nt] = __builtin_amdgcn_mfma_f32_16x16x32_bf16(af, bf[nt], accA[nt], 0, 0, 0);
        __syncthreads();
    }

    // ---- logits to attnL (C-frag: row p = wm*16+quad*4+r, col l) ----
    #pragma unroll
    for (int nt = 0; nt < 4; nt++)
        #pragma unroll
        for (int r = 0; r < 4; r++)
            attnL[(wm * 16 + quad * 4 + r) * PT + wn * 64 + nt * 16 + ln] = accA[nt][r];
    __syncthreads();

    // ---- phase B: softmax over valid slots, per column ----
    if (t < 128) {
        float m = -INFINITY;
        for (int p = 0; p < P; p++) m = fmaxf(m, attnL[p * PT + t]);
        float d = 0.f;
        for (int p = 0; p < P; p++) {
            float e = __expf(attnL[p * PT + t] - m);
            attnL[p * PT + t] = e;
            d += e;
        }
        float inv = 1.f / d;
        for (int p = 0; p < P; p++) attnL[p * PT + t] *= inv;
    }
    __syncthreads();

    // ---- convert attn -> Bs as attn^T bf16 [l][p], zero p >= P ----
    if (t < 128) {
        #pragma unroll
        for (int pp = 0; pp < 16; pp++) {
            float a = (2 * pp     < P) ? attnL[(2 * pp) * PT + t]     : 0.f;
            float c = (2 * pp + 1 < P) ? attnL[(2 * pp + 1) * PT + t] : 0.f;
            *(unsigned int*)(Bs + t * PBS + pp * 2) = pk_bf16(a, c);
        }
    }
    // ---- stage memT: mem_g[32p][256c] -> memS[256c][40] bf16 (p pairs) ----
    #pragma unroll
    for (int q = 0; q < 16; q++) {
        int idx = t + 256 * q;                 // 0..4095
        int c = idx & 255, pp = idx >> 8;      // p = 2*pp
        float va = mem_g[(size_t)(2 * pp)     * 256 + c];
        float vb = mem_g[(size_t)(2 * pp + 1) * 256 + c];
        *(unsigned int*)(memS + c * PMS + pp * 2) = pk_bf16(va, vb);
    }
    __syncthreads();

    // ---- phase C: aug = memT @ attn, one K=32 MFMA step, 2 c-passes ----
    short8 bfc[4];
    #pragma unroll
    for (int nt = 0; nt < 4; nt++) {
        const unsigned short* p = Bs + (wn * 64 + nt * 16 + ln) * PBS + quad * 8;
        union { short8 v; unsigned int u[4]; } r;
        r.u[0] = *(const unsigned int*)(p);
        r.u[1] = *(const unsigned int*)(p + 2);
        r.u[2] = *(const unsigned int*)(p + 4);
        r.u[3] = *(const unsigned int*)(p + 6);
        bfc[nt] = r.v;
    }
    const floatx4 zf = (floatx4){0.f, 0.f, 0.f, 0.f};
    for (int h = 0; h < 2; h++) {
        const int cbase = h * 128 + wm * 64;
        short8 afc[4];
        #pragma unroll
        for (int ct = 0; ct < 4; ct++)
            afc[ct] = *(const short8*)(memS + (cbase + ct * 16 + ln) * PMS + quad * 8);
        #pragma unroll
        for (int ct = 0; ct < 4; ct++) {
            floatx4 accC[4];
            #pragma unroll
            for (int nt = 0; nt < 4; nt++)
                accC[nt] = __builtin_amdgcn_mfma_f32_16x16x32_bf16(afc[ct], bfc[nt], zf, 0, 0, 0);
            #pragma unroll
            for (int r = 0; r < 4; r++) {
                int c = cbase + ct * 16 + quad * 4 + r;
                float* op = out + ((size_t)b * 512 + 256 + c) * HWD + l0 + wn * 64;
                #pragma unroll
                for (int nt = 0; nt < 4; nt++)
                    op[nt * 16 + ln] = accC[nt][r];
            }
        }
    }
}

// ---------------------------------------------------------------------------
extern "C" void kernel_launch(void* const* d_in, const int* in_sizes, int n_in,
                              void* d_out, int out_size, void* d_ws, size_t ws_size,
                              hipStream_t stream) {
    const float* feats = (const float*)d_in[0];
    const float* preds = (const float*)d_in[1];
    const float* W     = (const float*)d_in[2];
    const float* bias  = (const float*)d_in[3];
    const int*   epoch = (const int*)d_in[4];
    float* out = (float*)d_out;

    float* ws     = (float*)d_ws;
    float* pooled = ws;              // 32*256 floats (accumulated via atomics)
    float* mem_g  = ws + 8192;       // 32*256 floats
    int*   ptr_g  = (int*)(ws + 16384);

    hipMemsetAsync(pooled, 0, 8192 * sizeof(float), stream);

    k1_proj_gemm<<<dim3(2048), 256, 0, stream>>>(feats, preds, W, bias, out, pooled);
    k2_mem_update<<<1, 1024, 0, stream>>>(pooled, epoch, mem_g, ptr_g);
    k3_attention<<<dim3(32, 32), 256, 0, stream>>>(mem_g, ptr_g, out);
}